// Round 4
// baseline (137.203 us; speedup 1.0000x reference)
//
#include <hip/hip_runtime.h>

// Problem: B=32, N=128, T=96, H=64, TF=24. All I/O float32.
// A_norm = ones(N,N)/N => model collapses to per-batch H-vectors.
//
// R19: R18 null (split-acc/bias-in-C invisible) => chain not MFMA-dep bound.
// Rejected on paper: pi-relabel no-crosslane scheme (16x redundant tanh;
// TRANS quarter-rate kills it), 16-batch MFMA (same), swizzle-for-bperm
// (pattern not expressible). Remaining real cost: serial overheads AROUND
// the loop. Redo R17's fusion WITHOUT the spill: 512 threads (8 waves x
// 6 t-pairs = 48 exactly), __launch_bounds__(512,1) -> 256-VGPR cap, ODE
// B-frag/bias preamble hoisted BEFORE the barrier (overlaps wave0 spatial),
// h2/att in LDS, exp2-folded tanh. Expect fused ~38-41us, VGPR>=160
// (no-spill check), total ~121-124.

#define BN 32
#define NN 128
#define TT 96
#define HH 64
#define TFC 24

#if defined(__has_builtin)
#if __has_builtin(__builtin_amdgcn_fdot2)
#define HAVE_FDOT2 1
#endif
#if __has_builtin(__builtin_amdgcn_update_dpp)
#define HAVE_DPP 1
#endif
#if __has_builtin(__builtin_amdgcn_exp2f)
#define HAVE_EXP2 1
#endif
#endif

using half2v = __fp16 __attribute__((ext_vector_type(2)));
typedef _Float16 half8 __attribute__((ext_vector_type(8)));
typedef float f32x4 __attribute__((ext_vector_type(4)));

__device__ __forceinline__ unsigned pack_pair(float a, float b) {
    union { half2v h; unsigned u; } c;
    c.h = __builtin_amdgcn_cvt_pkrtz(a, b);
    return c.u;
}
__device__ __forceinline__ half2v as_h2(unsigned u) {
    union { unsigned u; half2v h; } c; c.u = u; return c.h;
}
__device__ __forceinline__ unsigned rdlu(unsigned v, int l) {
    return (unsigned)__builtin_amdgcn_readlane((int)v, l);
}
__device__ __forceinline__ float rdl(float v, int l) {
    return __int_as_float(__builtin_amdgcn_readlane(__float_as_int(v), l));
}

template <int CTRL>
__device__ __forceinline__ float dppf(float x) {
#if HAVE_DPP
    return __int_as_float(
        __builtin_amdgcn_update_dpp(0, __float_as_int(x), CTRL, 0xF, 0xF, true));
#else
    return 0.f;  // unused
#endif
}

__device__ __forceinline__ float xor1(float x) {
#if HAVE_DPP
    return dppf<0xB1>(x);          // quad_perm [1,0,3,2] — VALU pipe
#else
    return __shfl_xor(x, 1, 64);
#endif
}

__device__ __forceinline__ float wave_sum(float v) {
#if HAVE_DPP
    v += dppf<0xB1>(v);
    v += dppf<0x4E>(v);
    v += dppf<0x141>(v);
    v += dppf<0x140>(v);
    return ((rdl(v, 0) + rdl(v, 16)) + (rdl(v, 32) + rdl(v, 48)));
#else
#pragma unroll
    for (int off = 32; off > 0; off >>= 1) v += __shfl_xor(v, off, 64);
    return v;
#endif
}
__device__ __forceinline__ void wave_sum2(float& a, float& b) {
#if HAVE_DPP
    a += dppf<0xB1>(a);  b += dppf<0xB1>(b);
    a += dppf<0x4E>(a);  b += dppf<0x4E>(b);
    a += dppf<0x141>(a); b += dppf<0x141>(b);
    a += dppf<0x140>(a); b += dppf<0x140>(b);
    a = (rdl(a, 0) + rdl(a, 16)) + (rdl(a, 32) + rdl(a, 48));
    b = (rdl(b, 0) + rdl(b, 16)) + (rdl(b, 32) + rdl(b, 48));
#else
    a = wave_sum(a); b = wave_sum(b);
#endif
}
__device__ __forceinline__ float wave_max(float v) {
#if HAVE_DPP
    v = fmaxf(v, dppf<0xB1>(v));
    v = fmaxf(v, dppf<0x4E>(v));
    v = fmaxf(v, dppf<0x141>(v));
    v = fmaxf(v, dppf<0x140>(v));
    return fmaxf(fmaxf(rdl(v, 0), rdl(v, 16)), fmaxf(rdl(v, 32), rdl(v, 48)));
#else
#pragma unroll
    for (int off = 32; off > 0; off >>= 1) v = fmaxf(v, __shfl_xor(v, off, 64));
    return v;
#endif
}

__device__ __forceinline__ float dot2acc(unsigned w, unsigned up, float acc) {
#if HAVE_FDOT2
    return __builtin_amdgcn_fdot2(as_h2(w), as_h2(up), acc, false);
#else
    const half2v wh = as_h2(w), uh = as_h2(up);
    return fmaf((float)wh.y, (float)uh.y, fmaf((float)wh.x, (float)uh.x, acc));
#endif
}

// Dual-stream matvec (shared weights) for the spatial phase.
#define PMV64_2(WP, UA, UB, RA, RB)                                        \
    do {                                                                   \
        float a0 = 0.f, a1 = 0.f, a2 = 0.f, a3 = 0.f;                      \
        float b0 = 0.f, b1 = 0.f, b2 = 0.f, b3 = 0.f;                      \
        _Pragma("unroll")                                                  \
        for (int k = 0; k < 32; k += 4) {                                  \
            const unsigned ua0 = rdlu(UA, 2 * k);                          \
            const unsigned ub0 = rdlu(UB, 2 * k);                          \
            const unsigned ua1 = rdlu(UA, 2 * k + 2);                      \
            const unsigned ub1 = rdlu(UB, 2 * k + 2);                      \
            const unsigned ua2 = rdlu(UA, 2 * k + 4);                      \
            const unsigned ub2 = rdlu(UB, 2 * k + 4);                      \
            const unsigned ua3 = rdlu(UA, 2 * k + 6);                      \
            const unsigned ub3 = rdlu(UB, 2 * k + 6);                      \
            a0 = dot2acc(WP[k],     ua0, a0);                              \
            b0 = dot2acc(WP[k],     ub0, b0);                              \
            a1 = dot2acc(WP[k + 1], ua1, a1);                              \
            b1 = dot2acc(WP[k + 1], ub1, b1);                              \
            a2 = dot2acc(WP[k + 2], ua2, a2);                              \
            b2 = dot2acc(WP[k + 2], ub2, b2);                              \
            a3 = dot2acc(WP[k + 3], ua3, a3);                              \
            b3 = dot2acc(WP[k + 3], ub3, b3);                              \
        }                                                                  \
        RA = (a0 + a1) + (a2 + a3);                                       \
        RB = (b0 + b1) + (b2 + b3);                                       \
    } while (0)

// exp2-folded tanh: one dependent mul before v_exp (saves a dep vs 2x form).
// No clamp: x->+inf => rcp(inf)=0 => 1; x->-inf => e=0 => -1. (R13-proven)
__device__ __forceinline__ float fast_tanh(float x) {
#if HAVE_EXP2
    float e = __builtin_amdgcn_exp2f(x * 2.885390082f);   // 2^(2x*log2e)=e^{2x}
#else
    float e = __expf(2.f * x);
#endif
    return 1.f - 2.f * __builtin_amdgcn_rcpf(e + 1.f);
}
__device__ __forceinline__ float fast_sigmoid(float x) {
    return __builtin_amdgcn_rcpf(1.f + __expf(-x));
}

// ============================ Fused kernel ================================
// grid 32 (batch), block 512 (8 waves).
// Phase 1 (all 8 waves): spatial GCN + attention logits -> LDS. Wave w does
//   t-pairs 6w..6w+5 (same per-wave work as the split kernel). Wave 0 also
//   preloads ODE B-frags/biases BEFORE the barrier (overlaps others).
// Phase 2 (wave 0 only): softmax + nf + GRU + 23 RK4 steps + head.
__global__ __launch_bounds__(512, 1) void fused_kernel(
    const float* __restrict__ x,    const float* __restrict__ Ws1,
    const float* __restrict__ bs1,  const float* __restrict__ Ws2,
    const float* __restrict__ bs2,  const float* __restrict__ Wa1,
    const float* __restrict__ ba1,  const float* __restrict__ Wa2,
    const float* __restrict__ Wih,  const float* __restrict__ bih,
    const float* __restrict__ bhh,  const float* __restrict__ Wo1,
    const float* __restrict__ bo1p, const float* __restrict__ Wo2,
    const float* __restrict__ bo2p, const float* __restrict__ Wout,
    const float* __restrict__ boutp, float* __restrict__ out)
{
    const int tid  = threadIdx.x;
    const int lane = tid & 63;
    const int w    = tid >> 6;
    const int b    = blockIdx.x;

    __shared__ float xbar[TT];
    __shared__ unsigned h2s[(TT / 2) * HH];   // packed f16 t-pairs, 12 KB
    __shared__ float atts[TT];

    // ---- node-mean per t: threads 0..95, coalesced across t ----
    if (tid < TT) {
        const float* xb = x + (size_t)b * NN * TT + tid;
        float s = 0.f;
#pragma unroll
        for (int n = 0; n < NN; ++n) s += xb[n * TT];
        xbar[tid] = s * (1.f / 128.f);
    }

    // ---- ODE weight preamble (wave 0 only, BEFORE the barrier) ----
    // v_mfma_f32_16x16x32_f16 frags; A/B share the (grp,reg)->k map so any
    // k-permutation cancels; C select via m89-verified col=lane&15 map.
    const int col16 = lane & 15;
    const int grp   = lane >> 4;
    union Frag { unsigned u4[4]; half8 h; };
    Frag B1[4][2], B2[4][2];          // [N-tile][K-step]
    f32x4 BIAS1[4], BIAS2[4];
    if (w == 0) {
#pragma unroll
        for (int t = 0; t < 4; ++t) {
#pragma unroll
            for (int s = 0; s < 2; ++s) {
#pragma unroll
                for (int rr = 0; rr < 4; ++rr) {
                    const int k = 32 * s + 8 * grp + 2 * rr;
                    const int j = 16 * t + col16;
                    B1[t][s].u4[rr] = pack_pair(Wo1[k * HH + j], Wo1[(k + 1) * HH + j]);
                    B2[t][s].u4[rr] = pack_pair(Wo2[k * HH + j], Wo2[(k + 1) * HH + j]);
                }
            }
        }
        // Bias pre-splatted as C-input frags: after tile-select lane picks
        // b[16*grp + col16] = b[lane].
#pragma unroll
        for (int t = 0; t < 4; ++t) {
            const float b1v = bo1p[16 * t + col16];
            const float b2v = bo2p[16 * t + col16];
            BIAS1[t] = f32x4{b1v, b1v, b1v, b1v};
            BIAS2[t] = f32x4{b2v, b2v, b2v, b2v};
        }
#pragma unroll
        for (int t = 0; t < 4; ++t) {
#pragma unroll
            for (int s = 0; s < 2; ++s) {
                asm volatile("" : "+v"(B1[t][s].h), "+v"(B2[t][s].h));
            }
            asm volatile("" : "+v"(BIAS1[t]), "+v"(BIAS2[t]));
        }
    }

    // ---- per-lane spatial weights (packed f16 pairs, resident) ----
    const float ws1l = Ws1[lane];
    const float bs1l = bs1[lane];
    const float bs2l = bs2[lane];
    const float ba1l = ba1[lane];
    const float wa2l = Wa2[lane];
    unsigned ws2p[32], wa1p[32];
#pragma unroll
    for (int k = 0; k < 32; ++k) {
        ws2p[k] = pack_pair(Ws2[(2 * k) * HH + lane], Ws2[(2 * k + 1) * HH + lane]);
        wa1p[k] = pack_pair(Wa1[(2 * k) * HH + lane], Wa1[(2 * k + 1) * HH + lane]);
    }
#pragma unroll
    for (int k = 0; k < 32; ++k) {
        asm volatile("" : "+v"(ws2p[k]), "+v"(wa1p[k]));
    }
    __syncthreads();   // xbar ready

#pragma unroll 1
    for (int i = 0; i < 6; ++i) {
        const int tp  = w * 6 + i;              // t-pair index 0..47
        const int tl0 = 2 * tp;                 // even t
        const float sA = xbar[tl0];
        const float sB = xbar[tl0 + 1];
        const float h1A = fmaxf(fmaf(sA, ws1l, bs1l), 0.f);
        const float h1B = fmaxf(fmaf(sB, ws1l, bs1l), 0.f);
        const unsigned uA = pack_pair(h1A, xor1(h1A));
        const unsigned uB = pack_pair(h1B, xor1(h1B));
        float accA, accB;
        PMV64_2(ws2p, uA, uB, accA, accB);
        const float h2A = fmaxf(accA + bs2l, 0.f);
        const float h2B = fmaxf(accB + bs2l, 0.f);
        h2s[tp * HH + lane] = pack_pair(h2A, h2B);

        const unsigned vA = pack_pair(h2A, xor1(h2A));
        const unsigned vB = pack_pair(h2B, xor1(h2B));
        PMV64_2(wa1p, vA, vB, accA, accB);
        float gA = fast_tanh(accA + ba1l) * wa2l;
        float gB = fast_tanh(accB + ba1l) * wa2l;
        wave_sum2(gA, gB);                       // ba2: shift-invariant
        if (lane == 0) {
            atts[tl0]     = gA;
            atts[tl0 + 1] = gB;
        }
    }
    __syncthreads();   // h2s/atts ready

    if (w != 0) return;

    // ======================= ODE phase (wave 0) ==========================
    // ---- softmax over t (96 logits: lane t, lane 64+t for t<32) ----
    const float a0s = atts[lane];
    const float a1s = (lane < TT - 64) ? atts[64 + lane] : -1e30f;
    const float m = wave_max(fmaxf(a0s, a1s));
    const float e0 = __expf(a0s - m);
    const float e1 = (lane < TT - 64) ? __expf(a1s - m) : 0.f;
    const float inv = __builtin_amdgcn_rcpf(wave_sum(e0 + e1));
    const float q0 = e0 * inv;      // weight for t = lane
    const float q1 = e1 * inv;      // weight for t = 64 + lane (lane < 32)

    // ---- nf[lane] = sum_t w[t]*h2[t][lane] via packed t-pairs + dot2 ----
    float nf = 0.f;
#pragma unroll
    for (int tp = 0; tp < 32; ++tp) {
        const unsigned hpv = h2s[tp * HH + lane];
        const unsigned qp = pack_pair(rdl(q0, 2 * tp), rdl(q0, 2 * tp + 1));
        nf = dot2acc(hpv, qp, nf);
    }
#pragma unroll
    for (int tp = 32; tp < TT / 2; ++tp) {
        const unsigned hpv = h2s[tp * HH + lane];
        const unsigned qp = pack_pair(rdl(q1, 2 * tp - 64), rdl(q1, 2 * tp - 63));
        nf = dot2acc(hpv, qp, nf);
    }

    // ---- one-step GRU, h0=0 (W_hh matmul vanishes; b_hh biases remain) ----
    float gr = bih[lane];
    float gz = bih[64 + lane];
    float gn = bih[128 + lane];
#pragma unroll
    for (int j = 0; j < HH; j += 4) {
        const float4 wr = *(const float4*)&Wih[(size_t)lane * HH + j];
        const float4 wz = *(const float4*)&Wih[(size_t)(64 + lane) * HH + j];
        const float4 wn = *(const float4*)&Wih[(size_t)(128 + lane) * HH + j];
        const float n0 = rdl(nf, j), n1 = rdl(nf, j + 1);
        const float n2 = rdl(nf, j + 2), n3 = rdl(nf, j + 3);
        gr += n0 * wr.x + n1 * wr.y + n2 * wr.z + n3 * wr.w;
        gz += n0 * wz.x + n1 * wz.y + n2 * wz.z + n3 * wz.w;
        gn += n0 * wn.x + n1 * wn.y + n2 * wn.z + n3 * wn.w;
    }
    const float r = fast_sigmoid(gr + bhh[lane]);
    const float z = fast_sigmoid(gz + bhh[64 + lane]);
    const float n = fast_tanh(gn + r * bhh[128 + lane]);
    float y = (1.f - z) * n;

    const float wo  = Wout[lane];
    const float bo  = boutp[0];

    // bpermute byte addresses: A k-step 0 pulls pair m=4*grp+r from lane 2m;
    // k-step 1 pulls pair 16+4*grp+r (lanes 32..62).
    const int ab0 = 32 * grp;
    const bool s1 = (grp == 1), s2 = (grp == 2), s3 = (grp == 3);
    const f32x4 CZERO = {0.f, 0.f, 0.f, 0.f};

    auto f_eval = [&](float u) -> float {
        // ---- layer 1: 8 independent MFMAs (split accumulators) ----
        Frag A0, A1;
        const unsigned up = pack_pair(u, xor1(u));   // even lane 2m: (u[2m],u[2m+1])
#pragma unroll
        for (int rr = 0; rr < 4; ++rr) {
            A0.u4[rr] = (unsigned)__builtin_amdgcn_ds_bpermute(ab0 + 8 * rr, (int)up);
            A1.u4[rr] = (unsigned)__builtin_amdgcn_ds_bpermute(ab0 + 128 + 8 * rr, (int)up);
        }
        f32x4 c0 = __builtin_amdgcn_mfma_f32_16x16x32_f16(A0.h, B1[0][0].h, BIAS1[0], 0, 0, 0);
        f32x4 c1 = __builtin_amdgcn_mfma_f32_16x16x32_f16(A0.h, B1[1][0].h, BIAS1[1], 0, 0, 0);
        f32x4 c2 = __builtin_amdgcn_mfma_f32_16x16x32_f16(A0.h, B1[2][0].h, BIAS1[2], 0, 0, 0);
        f32x4 c3 = __builtin_amdgcn_mfma_f32_16x16x32_f16(A0.h, B1[3][0].h, BIAS1[3], 0, 0, 0);
        f32x4 d0 = __builtin_amdgcn_mfma_f32_16x16x32_f16(A1.h, B1[0][1].h, CZERO, 0, 0, 0);
        f32x4 d1 = __builtin_amdgcn_mfma_f32_16x16x32_f16(A1.h, B1[1][1].h, CZERO, 0, 0, 0);
        f32x4 d2 = __builtin_amdgcn_mfma_f32_16x16x32_f16(A1.h, B1[2][1].h, CZERO, 0, 0, 0);
        f32x4 d3 = __builtin_amdgcn_mfma_f32_16x16x32_f16(A1.h, B1[3][1].h, CZERO, 0, 0, 0);
        const float e0v = c0[0] + d0[0];
        const float e1v = c1[0] + d1[0];
        const float e2v = c2[0] + d2[0];
        const float e3v = c3[0] + d3[0];
        float v = s1 ? e1v : e0v;
        v = s2 ? e2v : v;
        v = s3 ? e3v : v;                 // out[lane] + b1[lane], rows redundant
        v = fast_tanh(v);
        // ---- layer 2 ----
        const unsigned vp = pack_pair(v, xor1(v));
#pragma unroll
        for (int rr = 0; rr < 4; ++rr) {
            A0.u4[rr] = (unsigned)__builtin_amdgcn_ds_bpermute(ab0 + 8 * rr, (int)vp);
            A1.u4[rr] = (unsigned)__builtin_amdgcn_ds_bpermute(ab0 + 128 + 8 * rr, (int)vp);
        }
        c0 = __builtin_amdgcn_mfma_f32_16x16x32_f16(A0.h, B2[0][0].h, BIAS2[0], 0, 0, 0);
        c1 = __builtin_amdgcn_mfma_f32_16x16x32_f16(A0.h, B2[1][0].h, BIAS2[1], 0, 0, 0);
        c2 = __builtin_amdgcn_mfma_f32_16x16x32_f16(A0.h, B2[2][0].h, BIAS2[2], 0, 0, 0);
        c3 = __builtin_amdgcn_mfma_f32_16x16x32_f16(A0.h, B2[3][0].h, BIAS2[3], 0, 0, 0);
        d0 = __builtin_amdgcn_mfma_f32_16x16x32_f16(A1.h, B2[0][1].h, CZERO, 0, 0, 0);
        d1 = __builtin_amdgcn_mfma_f32_16x16x32_f16(A1.h, B2[1][1].h, CZERO, 0, 0, 0);
        d2 = __builtin_amdgcn_mfma_f32_16x16x32_f16(A1.h, B2[2][1].h, CZERO, 0, 0, 0);
        d3 = __builtin_amdgcn_mfma_f32_16x16x32_f16(A1.h, B2[3][1].h, CZERO, 0, 0, 0);
        const float g0v = c0[0] + d0[0];
        const float g1v = c1[0] + d1[0];
        const float g2v = c2[0] + d2[0];
        const float g3v = c3[0] + d3[0];
        float o = s1 ? g1v : g0v;
        o = s2 ? g2v : o;
        o = s3 ? g3v : o;
        return fast_tanh(o);
    };

    float* ob = out + (size_t)b * NN * TFC;
    {
        const float p = wave_sum(y * wo) + bo;     // traj[0] = hidden
        ob[lane * TFC]        = p;
        ob[(64 + lane) * TFC] = p;
    }

    const float dt = (float)(24.0 / 23.0);
    const float third = 1.f / 3.f;

#pragma unroll 1
    for (int st = 0; st < TFC - 1; ++st) {
        const float k1 = f_eval(y);
        const float k2 = f_eval(y + dt * k1 * third);
        const float k3 = f_eval(y + dt * (k2 - k1 * third));
        const float k4 = f_eval(y + dt * (k1 - k2 + k3));
        y = y + dt * (k1 + 3.f * (k2 + k3) + k4) * 0.125f;
        const float p = wave_sum(y * wo) + bo;
        ob[lane * TFC + st + 1]        = p;
        ob[(64 + lane) * TFC + st + 1] = p;
    }
}

extern "C" void kernel_launch(void* const* d_in, const int* in_sizes, int n_in,
                              void* d_out, int out_size, void* d_ws, size_t ws_size,
                              hipStream_t stream) {
    (void)in_sizes; (void)n_in; (void)ws_size; (void)out_size; (void)d_ws;
    const float* x    = (const float*)d_in[0];
    const float* Ws1  = (const float*)d_in[1];
    const float* bs1  = (const float*)d_in[2];
    const float* Ws2  = (const float*)d_in[3];
    const float* bs2  = (const float*)d_in[4];
    const float* Wa1  = (const float*)d_in[5];
    const float* ba1  = (const float*)d_in[6];
    const float* Wa2  = (const float*)d_in[7];
    // d_in[8]  = ba2  : unused (softmax shift-invariant)
    const float* Wih  = (const float*)d_in[9];
    // d_in[10] = W_hh : unused (h0 = 0)
    const float* bih  = (const float*)d_in[11];
    const float* bhh  = (const float*)d_in[12];
    const float* Wo1  = (const float*)d_in[13];
    const float* bo1  = (const float*)d_in[14];
    const float* Wo2  = (const float*)d_in[15];
    const float* bo2  = (const float*)d_in[16];
    const float* Wout = (const float*)d_in[17];
    const float* bout = (const float*)d_in[18];

    fused_kernel<<<dim3(BN), dim3(512), 0, stream>>>(
        x, Ws1, bs1, Ws2, bs2, Wa1, ba1, Wa2,
        Wih, bih, bhh, Wo1, bo1, Wo2, bo2, Wout, bout,
        (float*)d_out);
}

// Round 5
// 136.762 us; speedup vs baseline: 1.0032x; 1.0032x over previous
//
#include <hip/hip_runtime.h>

// Problem: B=32, N=128, T=96, H=64, TF=24. All I/O float32.
// A_norm = ones(N,N)/N => model collapses to per-batch H-vectors.
//
// R20: R19 fused-512 regressed (spill + 2x per-wave spatial) => back to the
// split R18 base. ODE chain ~460cyc/layer across 3 rewrites; the one big
// rock on the critical path is the 8x ds_bpermute gather (~160cyc DS wait).
// This round removes ALL DS from the loop: state kept DISTRIBUTED
// (lane(g,c) holds z[16t+c], t=0..3); per layer: 4 packs -> 4 broadcast-
// MFMAs (constant one-hot-row B_sel: C = A*B_sel replicates column sigma(2t)
// of A across all cols — lane(g,c) gets u[16t+4g+r] in C rows 4g+r, m89 row
// map) -> 8 lane-local packs build next A-frag -> 8 weight-MFMAs with
// k-relabeled B (rows at u_idx=16(2ks+s)+4g+rr; A/B agree => legal) ->
// 4 tanhs. Slot-space symmetric => immune to any shared K-permutation
// (validated by R16 passing). f16 precision bit-identical. GRU y
// distributed once via 4 bpermutes; head uses 0.25-scaled Wout (4x group
// redundancy). Predict ode 36 -> ~18-25us, total ~110-118.

#define BN 32
#define NN 128
#define TT 96
#define HH 64
#define TFC 24

#if defined(__has_builtin)
#if __has_builtin(__builtin_amdgcn_fdot2)
#define HAVE_FDOT2 1
#endif
#if __has_builtin(__builtin_amdgcn_update_dpp)
#define HAVE_DPP 1
#endif
#if __has_builtin(__builtin_amdgcn_exp2f)
#define HAVE_EXP2 1
#endif
#endif

using half2v = __fp16 __attribute__((ext_vector_type(2)));
typedef _Float16 half8 __attribute__((ext_vector_type(8)));
typedef float f32x4 __attribute__((ext_vector_type(4)));

__device__ __forceinline__ unsigned pack_pair(float a, float b) {
    union { half2v h; unsigned u; } c;
    c.h = __builtin_amdgcn_cvt_pkrtz(a, b);
    return c.u;
}
__device__ __forceinline__ half2v as_h2(unsigned u) {
    union { unsigned u; half2v h; } c; c.u = u; return c.h;
}
__device__ __forceinline__ unsigned rdlu(unsigned v, int l) {
    return (unsigned)__builtin_amdgcn_readlane((int)v, l);
}
__device__ __forceinline__ float rdl(float v, int l) {
    return __int_as_float(__builtin_amdgcn_readlane(__float_as_int(v), l));
}

template <int CTRL>
__device__ __forceinline__ float dppf(float x) {
#if HAVE_DPP
    return __int_as_float(
        __builtin_amdgcn_update_dpp(0, __float_as_int(x), CTRL, 0xF, 0xF, true));
#else
    return 0.f;  // unused
#endif
}

__device__ __forceinline__ float xor1(float x) {
#if HAVE_DPP
    return dppf<0xB1>(x);          // quad_perm [1,0,3,2] — VALU pipe
#else
    return __shfl_xor(x, 1, 64);
#endif
}

__device__ __forceinline__ float wave_sum(float v) {
#if HAVE_DPP
    v += dppf<0xB1>(v);
    v += dppf<0x4E>(v);
    v += dppf<0x141>(v);
    v += dppf<0x140>(v);
    return ((rdl(v, 0) + rdl(v, 16)) + (rdl(v, 32) + rdl(v, 48)));
#else
#pragma unroll
    for (int off = 32; off > 0; off >>= 1) v += __shfl_xor(v, off, 64);
    return v;
#endif
}
__device__ __forceinline__ void wave_sum2(float& a, float& b) {
#if HAVE_DPP
    a += dppf<0xB1>(a);  b += dppf<0xB1>(b);
    a += dppf<0x4E>(a);  b += dppf<0x4E>(b);
    a += dppf<0x141>(a); b += dppf<0x141>(b);
    a += dppf<0x140>(a); b += dppf<0x140>(b);
    a = (rdl(a, 0) + rdl(a, 16)) + (rdl(a, 32) + rdl(a, 48));
    b = (rdl(b, 0) + rdl(b, 16)) + (rdl(b, 32) + rdl(b, 48));
#else
    a = wave_sum(a); b = wave_sum(b);
#endif
}
__device__ __forceinline__ float wave_max(float v) {
#if HAVE_DPP
    v = fmaxf(v, dppf<0xB1>(v));
    v = fmaxf(v, dppf<0x4E>(v));
    v = fmaxf(v, dppf<0x141>(v));
    v = fmaxf(v, dppf<0x140>(v));
    return fmaxf(fmaxf(rdl(v, 0), rdl(v, 16)), fmaxf(rdl(v, 32), rdl(v, 48)));
#else
#pragma unroll
    for (int off = 32; off > 0; off >>= 1) v = fmaxf(v, __shfl_xor(v, off, 64));
    return v;
#endif
}

__device__ __forceinline__ float dot2acc(unsigned w, unsigned up, float acc) {
#if HAVE_FDOT2
    return __builtin_amdgcn_fdot2(as_h2(w), as_h2(up), acc, false);
#else
    const half2v wh = as_h2(w), uh = as_h2(up);
    return fmaf((float)wh.y, (float)uh.y, fmaf((float)wh.x, (float)uh.x, acc));
#endif
}

// Dual-stream matvec (shared weights) for the spatial phase.
#define PMV64_2(WP, UA, UB, RA, RB)                                        \
    do {                                                                   \
        float a0 = 0.f, a1 = 0.f, a2 = 0.f, a3 = 0.f;                      \
        float b0 = 0.f, b1 = 0.f, b2 = 0.f, b3 = 0.f;                      \
        _Pragma("unroll")                                                  \
        for (int k = 0; k < 32; k += 4) {                                  \
            const unsigned ua0 = rdlu(UA, 2 * k);                          \
            const unsigned ub0 = rdlu(UB, 2 * k);                          \
            const unsigned ua1 = rdlu(UA, 2 * k + 2);                      \
            const unsigned ub1 = rdlu(UB, 2 * k + 2);                      \
            const unsigned ua2 = rdlu(UA, 2 * k + 4);                      \
            const unsigned ub2 = rdlu(UB, 2 * k + 4);                      \
            const unsigned ua3 = rdlu(UA, 2 * k + 6);                      \
            const unsigned ub3 = rdlu(UB, 2 * k + 6);                      \
            a0 = dot2acc(WP[k],     ua0, a0);                              \
            b0 = dot2acc(WP[k],     ub0, b0);                              \
            a1 = dot2acc(WP[k + 1], ua1, a1);                              \
            b1 = dot2acc(WP[k + 1], ub1, b1);                              \
            a2 = dot2acc(WP[k + 2], ua2, a2);                              \
            b2 = dot2acc(WP[k + 2], ub2, b2);                              \
            a3 = dot2acc(WP[k + 3], ua3, a3);                              \
            b3 = dot2acc(WP[k + 3], ub3, b3);                              \
        }                                                                  \
        RA = (a0 + a1) + (a2 + a3);                                       \
        RB = (b0 + b1) + (b2 + b3);                                       \
    } while (0)

// exp2-folded tanh. No clamp: x->+inf => 1; x->-inf => -1. (R13-proven)
__device__ __forceinline__ float fast_tanh(float x) {
#if HAVE_EXP2
    float e = __builtin_amdgcn_exp2f(x * 2.885390082f);   // 2^(2x*log2e)=e^{2x}
#else
    float e = __expf(2.f * x);
#endif
    return 1.f - 2.f * __builtin_amdgcn_rcpf(e + 1.f);
}
__device__ __forceinline__ float fast_sigmoid(float x) {
    return __builtin_amdgcn_rcpf(1.f + __expf(-x));
}

// ============================ Kernel A ====================================
// grid (4, 32): block = (t-quarter, batch). 4 waves x 6 t (3 dual-iters).
__global__ __launch_bounds__(256) void spatial_kernel(
    const float* __restrict__ x,    const float* __restrict__ Ws1,
    const float* __restrict__ bs1,  const float* __restrict__ Ws2,
    const float* __restrict__ bs2,  const float* __restrict__ Wa1,
    const float* __restrict__ ba1,  const float* __restrict__ Wa2,
    unsigned* __restrict__ ws_h2,   float* __restrict__ ws_att)
{
    const int tid  = threadIdx.x;
    const int lane = tid & 63;
    const int w    = tid >> 6;
    const int tq   = blockIdx.x;
    const int b    = blockIdx.y;
    const int tbase = tq * 24;

    __shared__ float xbar[24];
    if (tid < 24) {
        const float* xb = x + (size_t)b * NN * TT + (tbase + tid);
        float s = 0.f;
#pragma unroll
        for (int n = 0; n < NN; ++n) s += xb[n * TT];
        xbar[tid] = s * (1.f / 128.f);
    }

    const float ws1l = Ws1[lane];
    const float bs1l = bs1[lane];
    const float bs2l = bs2[lane];
    const float ba1l = ba1[lane];
    const float wa2l = Wa2[lane];
    unsigned ws2p[32], wa1p[32];
#pragma unroll
    for (int k = 0; k < 32; ++k) {
        ws2p[k] = pack_pair(Ws2[(2 * k) * HH + lane], Ws2[(2 * k + 1) * HH + lane]);
        wa1p[k] = pack_pair(Wa1[(2 * k) * HH + lane], Wa1[(2 * k + 1) * HH + lane]);
    }
#pragma unroll
    for (int k = 0; k < 32; ++k) {
        asm volatile("" : "+v"(ws2p[k]), "+v"(wa1p[k]));
    }
    __syncthreads();   // xbar ready

#pragma unroll 1
    for (int i = 0; i < 3; ++i) {
        const int tl0 = w * 6 + 2 * i;          // local t (even)
        const float sA = xbar[tl0];
        const float sB = xbar[tl0 + 1];
        const float h1A = fmaxf(fmaf(sA, ws1l, bs1l), 0.f);
        const float h1B = fmaxf(fmaf(sB, ws1l, bs1l), 0.f);
        const unsigned uA = pack_pair(h1A, xor1(h1A));
        const unsigned uB = pack_pair(h1B, xor1(h1B));
        float accA, accB;
        PMV64_2(ws2p, uA, uB, accA, accB);
        const float h2A = fmaxf(accA + bs2l, 0.f);
        const float h2B = fmaxf(accB + bs2l, 0.f);
        ws_h2[((size_t)b * (TT / 2) + (tbase + tl0) / 2) * HH + lane] =
            pack_pair(h2A, h2B);

        const unsigned vA = pack_pair(h2A, xor1(h2A));
        const unsigned vB = pack_pair(h2B, xor1(h2B));
        PMV64_2(wa1p, vA, vB, accA, accB);
        float gA = fast_tanh(accA + ba1l) * wa2l;
        float gB = fast_tanh(accB + ba1l) * wa2l;
        wave_sum2(gA, gB);                       // ba2: shift-invariant
        if (lane == 0) {
            ws_att[b * TT + tbase + tl0]     = gA;
            ws_att[b * TT + tbase + tl0 + 1] = gB;
        }
    }
}

// ============================ Kernel B ====================================
// grid 32 x 64 threads: softmax + nf + GRU + 23 RK4 steps + head.
// ODE state DISTRIBUTED: lane(g,c) holds y[16t+c] for t=0..3. No DS in loop.
__global__ __launch_bounds__(64)
__attribute__((amdgpu_waves_per_eu(1, 1)))
void ode_kernel(
    const unsigned* __restrict__ ws_h2, const float* __restrict__ ws_att,
    const float* __restrict__ Wih,  const float* __restrict__ bih,
    const float* __restrict__ bhh,  const float* __restrict__ Wo1,
    const float* __restrict__ bo1p, const float* __restrict__ Wo2,
    const float* __restrict__ bo2p, const float* __restrict__ Wout,
    const float* __restrict__ boutp, float* __restrict__ out)
{
    const int lane = threadIdx.x;
    const int b    = blockIdx.x;
    const int col16 = lane & 15;
    const int grp   = lane >> 4;

    // ---- softmax over t (96 logits: lane t, lane 64+t for t<32) ----
    const float a0s = ws_att[b * TT + lane];
    const float a1s = (lane < TT - 64) ? ws_att[b * TT + 64 + lane] : -1e30f;
    const float m = wave_max(fmaxf(a0s, a1s));
    const float e0 = __expf(a0s - m);
    const float e1 = (lane < TT - 64) ? __expf(a1s - m) : 0.f;
    const float inv = __builtin_amdgcn_rcpf(wave_sum(e0 + e1));
    const float q0 = e0 * inv;      // weight for t = lane
    const float q1 = e1 * inv;      // weight for t = 64 + lane (lane < 32)

    // ---- nf[lane] = sum_t w[t]*h2[t][lane] via packed t-pairs + dot2 ----
    const unsigned* h2b = ws_h2 + (size_t)b * (TT / 2) * HH;
    unsigned hp[TT / 2];
#pragma unroll
    for (int tp = 0; tp < TT / 2; ++tp) hp[tp] = h2b[tp * HH + lane];
    float nf = 0.f;
#pragma unroll
    for (int tp = 0; tp < 32; ++tp) {
        const unsigned qp = pack_pair(rdl(q0, 2 * tp), rdl(q0, 2 * tp + 1));
        nf = dot2acc(hp[tp], qp, nf);
    }
#pragma unroll
    for (int tp = 32; tp < TT / 2; ++tp) {
        const unsigned qp = pack_pair(rdl(q1, 2 * tp - 64), rdl(q1, 2 * tp - 63));
        nf = dot2acc(hp[tp], qp, nf);
    }

    // ---- one-step GRU, h0=0 (W_hh matmul vanishes; b_hh biases remain) ----
    float gr = bih[lane];
    float gz = bih[64 + lane];
    float gn = bih[128 + lane];
#pragma unroll
    for (int j = 0; j < HH; j += 4) {
        const float4 wr = *(const float4*)&Wih[(size_t)lane * HH + j];
        const float4 wz = *(const float4*)&Wih[(size_t)(64 + lane) * HH + j];
        const float4 wn = *(const float4*)&Wih[(size_t)(128 + lane) * HH + j];
        const float n0 = rdl(nf, j), n1 = rdl(nf, j + 1);
        const float n2 = rdl(nf, j + 2), n3 = rdl(nf, j + 3);
        gr += n0 * wr.x + n1 * wr.y + n2 * wr.z + n3 * wr.w;
        gz += n0 * wz.x + n1 * wz.y + n2 * wz.z + n3 * wz.w;
        gn += n0 * wn.x + n1 * wn.y + n2 * wn.z + n3 * wn.w;
    }
    const float r = fast_sigmoid(gr + bhh[lane]);
    const float z = fast_sigmoid(gz + bhh[64 + lane]);
    const float n = fast_tanh(gn + r * bhh[128 + lane]);
    const float yl = (1.f - z) * n;           // y[lane]

    // ---- distribute y once: y_t = y[16t + col16] (4 one-time bpermutes) --
    float y0 = __int_as_float(__builtin_amdgcn_ds_bpermute(4 * (col16),      __float_as_int(yl)));
    float y1 = __int_as_float(__builtin_amdgcn_ds_bpermute(4 * (16 + col16), __float_as_int(yl)));
    float y2 = __int_as_float(__builtin_amdgcn_ds_bpermute(4 * (32 + col16), __float_as_int(yl)));
    float y3 = __int_as_float(__builtin_amdgcn_ds_bpermute(4 * (48 + col16), __float_as_int(yl)));

    // ---- weight fragments (k-relabeled rows: u_idx = 16*(2ks+s)+4g+rr) ----
    union Frag { unsigned u4[4]; half8 h; };
    Frag B1[4][2], B2[4][2];          // [N-tile][K-step]
#pragma unroll
    for (int t = 0; t < 4; ++t) {
#pragma unroll
        for (int s = 0; s < 2; ++s) {
#pragma unroll
            for (int rr = 0; rr < 4; ++rr) {
                const int i0 = 32 * s + 4 * grp + rr;        // 16*(2s)+4g+rr
                const int i1 = 32 * s + 16 + 4 * grp + rr;   // 16*(2s+1)+4g+rr
                const int j  = 16 * t + col16;
                B1[t][s].u4[rr] = pack_pair(Wo1[i0 * HH + j], Wo1[i1 * HH + j]);
                B2[t][s].u4[rr] = pack_pair(Wo2[i0 * HH + j], Wo2[i1 * HH + j]);
            }
        }
    }
    // Broadcast selectors: B_sel_t = one-hot at slot (g=0, dword t, low half)
    // => matrix row sigma(2t) all-ones => C = column sigma(2t) of A replicated.
    const unsigned selv = (grp == 0) ? 0x00003C00u : 0u;   // f16 1.0 low half
    Frag BS[4];
#pragma unroll
    for (int t = 0; t < 4; ++t) {
#pragma unroll
        for (int rr = 0; rr < 4; ++rr) BS[t].u4[rr] = (rr == t) ? selv : 0u;
    }
    // Bias pre-splatted as C-input frags: lane reads row 4g+reg, col c =>
    // value bias[16*tile + col16] (rows redundant).
    f32x4 BIAS1[4], BIAS2[4];
#pragma unroll
    for (int t = 0; t < 4; ++t) {
        const float b1v = bo1p[16 * t + col16];
        const float b2v = bo2p[16 * t + col16];
        BIAS1[t] = f32x4{b1v, b1v, b1v, b1v};
        BIAS2[t] = f32x4{b2v, b2v, b2v, b2v};
    }
#pragma unroll
    for (int t = 0; t < 4; ++t) {
#pragma unroll
        for (int s = 0; s < 2; ++s) {
            asm volatile("" : "+v"(B1[t][s].h), "+v"(B2[t][s].h));
        }
        asm volatile("" : "+v"(BS[t].h));
        asm volatile("" : "+v"(BIAS1[t]), "+v"(BIAS2[t]));
    }
    // Head weights: 0.25 cancels the 4x group redundancy in wave_sum.
    const float wo0 = 0.25f * Wout[col16];
    const float wo1 = 0.25f * Wout[16 + col16];
    const float wo2 = 0.25f * Wout[32 + col16];
    const float wo3 = 0.25f * Wout[48 + col16];
    const float bo  = boutp[0];

    const f32x4 CZERO = {0.f, 0.f, 0.f, 0.f};

    // f(z) distributed->distributed: two layers, zero cross-lane ops.
    auto f_eval = [&](float z0, float z1, float z2, float z3,
                      float& o0, float& o1, float& o2, float& o3) {
        // layer 1: pack z -> broadcast -> W1 matvec -> tanh
        Frag Au;
        Au.u4[0] = pack_pair(z0, z0);
        Au.u4[1] = pack_pair(z1, z1);
        Au.u4[2] = pack_pair(z2, z2);
        Au.u4[3] = pack_pair(z3, z3);
        f32x4 cb0 = __builtin_amdgcn_mfma_f32_16x16x32_f16(Au.h, BS[0].h, CZERO, 0, 0, 0);
        f32x4 cb1 = __builtin_amdgcn_mfma_f32_16x16x32_f16(Au.h, BS[1].h, CZERO, 0, 0, 0);
        f32x4 cb2 = __builtin_amdgcn_mfma_f32_16x16x32_f16(Au.h, BS[2].h, CZERO, 0, 0, 0);
        f32x4 cb3 = __builtin_amdgcn_mfma_f32_16x16x32_f16(Au.h, BS[3].h, CZERO, 0, 0, 0);
        // cb_t[reg] = z[16t + 4g + reg] (m89 row map) — lane-local A assembly
        Frag A0, A1;
#pragma unroll
        for (int rr = 0; rr < 4; ++rr) {
            A0.u4[rr] = pack_pair(cb0[rr], cb1[rr]);   // kstep0: u[4g+rr], u[16+4g+rr]
            A1.u4[rr] = pack_pair(cb2[rr], cb3[rr]);   // kstep1: u[32+..], u[48+..]
        }
        f32x4 c0 = __builtin_amdgcn_mfma_f32_16x16x32_f16(A1.h, B1[0][1].h,
                   __builtin_amdgcn_mfma_f32_16x16x32_f16(A0.h, B1[0][0].h, BIAS1[0], 0, 0, 0), 0, 0, 0);
        f32x4 c1 = __builtin_amdgcn_mfma_f32_16x16x32_f16(A1.h, B1[1][1].h,
                   __builtin_amdgcn_mfma_f32_16x16x32_f16(A0.h, B1[1][0].h, BIAS1[1], 0, 0, 0), 0, 0, 0);
        f32x4 c2 = __builtin_amdgcn_mfma_f32_16x16x32_f16(A1.h, B1[2][1].h,
                   __builtin_amdgcn_mfma_f32_16x16x32_f16(A0.h, B1[2][0].h, BIAS1[2], 0, 0, 0), 0, 0, 0);
        f32x4 c3 = __builtin_amdgcn_mfma_f32_16x16x32_f16(A1.h, B1[3][1].h,
                   __builtin_amdgcn_mfma_f32_16x16x32_f16(A0.h, B1[3][0].h, BIAS1[3], 0, 0, 0), 0, 0, 0);
        const float v0 = fast_tanh(c0[0]);
        const float v1 = fast_tanh(c1[0]);
        const float v2 = fast_tanh(c2[0]);
        const float v3 = fast_tanh(c3[0]);
        // layer 2: same machinery with W2
        Au.u4[0] = pack_pair(v0, v0);
        Au.u4[1] = pack_pair(v1, v1);
        Au.u4[2] = pack_pair(v2, v2);
        Au.u4[3] = pack_pair(v3, v3);
        cb0 = __builtin_amdgcn_mfma_f32_16x16x32_f16(Au.h, BS[0].h, CZERO, 0, 0, 0);
        cb1 = __builtin_amdgcn_mfma_f32_16x16x32_f16(Au.h, BS[1].h, CZERO, 0, 0, 0);
        cb2 = __builtin_amdgcn_mfma_f32_16x16x32_f16(Au.h, BS[2].h, CZERO, 0, 0, 0);
        cb3 = __builtin_amdgcn_mfma_f32_16x16x32_f16(Au.h, BS[3].h, CZERO, 0, 0, 0);
#pragma unroll
        for (int rr = 0; rr < 4; ++rr) {
            A0.u4[rr] = pack_pair(cb0[rr], cb1[rr]);
            A1.u4[rr] = pack_pair(cb2[rr], cb3[rr]);
        }
        c0 = __builtin_amdgcn_mfma_f32_16x16x32_f16(A1.h, B2[0][1].h,
             __builtin_amdgcn_mfma_f32_16x16x32_f16(A0.h, B2[0][0].h, BIAS2[0], 0, 0, 0), 0, 0, 0);
        c1 = __builtin_amdgcn_mfma_f32_16x16x32_f16(A1.h, B2[1][1].h,
             __builtin_amdgcn_mfma_f32_16x16x32_f16(A0.h, B2[1][0].h, BIAS2[1], 0, 0, 0), 0, 0, 0);
        c2 = __builtin_amdgcn_mfma_f32_16x16x32_f16(A1.h, B2[2][1].h,
             __builtin_amdgcn_mfma_f32_16x16x32_f16(A0.h, B2[2][0].h, BIAS2[2], 0, 0, 0), 0, 0, 0);
        c3 = __builtin_amdgcn_mfma_f32_16x16x32_f16(A1.h, B2[3][1].h,
             __builtin_amdgcn_mfma_f32_16x16x32_f16(A0.h, B2[3][0].h, BIAS2[3], 0, 0, 0), 0, 0, 0);
        o0 = fast_tanh(c0[0]);
        o1 = fast_tanh(c1[0]);
        o2 = fast_tanh(c2[0]);
        o3 = fast_tanh(c3[0]);
    };

    float* ob = out + (size_t)b * NN * TFC;
    {
        const float p = wave_sum(y0 * wo0 + y1 * wo1 + y2 * wo2 + y3 * wo3) + bo;
        ob[lane * TFC]        = p;
        ob[(64 + lane) * TFC] = p;
    }

    const float dt = (float)(24.0 / 23.0);
    const float third = 1.f / 3.f;
    const float dt3 = dt * third;

#pragma unroll 1
    for (int st = 0; st < TFC - 1; ++st) {
        float k10, k11, k12, k13, k20, k21, k22, k23;
        float k30, k31, k32, k33, k40, k41, k42, k43;
        f_eval(y0, y1, y2, y3, k10, k11, k12, k13);
        f_eval(y0 + dt3 * k10, y1 + dt3 * k11, y2 + dt3 * k12, y3 + dt3 * k13,
               k20, k21, k22, k23);
        f_eval(y0 + dt * (k20 - third * k10), y1 + dt * (k21 - third * k11),
               y2 + dt * (k22 - third * k12), y3 + dt * (k23 - third * k13),
               k30, k31, k32, k33);
        f_eval(y0 + dt * (k10 - k20 + k30), y1 + dt * (k11 - k21 + k31),
               y2 + dt * (k12 - k22 + k32), y3 + dt * (k13 - k23 + k33),
               k40, k41, k42, k43);
        y0 += dt * (k10 + 3.f * (k20 + k30) + k40) * 0.125f;
        y1 += dt * (k11 + 3.f * (k21 + k31) + k41) * 0.125f;
        y2 += dt * (k12 + 3.f * (k22 + k32) + k42) * 0.125f;
        y3 += dt * (k13 + 3.f * (k23 + k33) + k43) * 0.125f;
        const float p = wave_sum(y0 * wo0 + y1 * wo1 + y2 * wo2 + y3 * wo3) + bo;
        ob[lane * TFC + st + 1]        = p;
        ob[(64 + lane) * TFC + st + 1] = p;
    }
}

extern "C" void kernel_launch(void* const* d_in, const int* in_sizes, int n_in,
                              void* d_out, int out_size, void* d_ws, size_t ws_size,
                              hipStream_t stream) {
    (void)in_sizes; (void)n_in; (void)ws_size; (void)out_size;
    const float* x    = (const float*)d_in[0];
    const float* Ws1  = (const float*)d_in[1];
    const float* bs1  = (const float*)d_in[2];
    const float* Ws2  = (const float*)d_in[3];
    const float* bs2  = (const float*)d_in[4];
    const float* Wa1  = (const float*)d_in[5];
    const float* ba1  = (const float*)d_in[6];
    const float* Wa2  = (const float*)d_in[7];
    // d_in[8]  = ba2  : unused (softmax shift-invariant)
    const float* Wih  = (const float*)d_in[9];
    // d_in[10] = W_hh : unused (h0 = 0)
    const float* bih  = (const float*)d_in[11];
    const float* bhh  = (const float*)d_in[12];
    const float* Wo1  = (const float*)d_in[13];
    const float* bo1  = (const float*)d_in[14];
    const float* Wo2  = (const float*)d_in[15];
    const float* bo2  = (const float*)d_in[16];
    const float* Wout = (const float*)d_in[17];
    const float* bout = (const float*)d_in[18];

    unsigned* ws_h2 = (unsigned*)d_ws;                       // 32*48*64*4 = 384KB
    float* ws_att   = (float*)((char*)d_ws + (size_t)BN * (TT / 2) * HH * 4);

    spatial_kernel<<<dim3(4, BN), dim3(256), 0, stream>>>(
        x, Ws1, bs1, Ws2, bs2, Wa1, ba1, Wa2, ws_h2, ws_att);

    ode_kernel<<<dim3(BN), dim3(64), 0, stream>>>(
        ws_h2, ws_att, Wih, bih, bhh, Wo1, bo1, Wo2, bo2, Wout, bout,
        (float*)d_out);
}

// Round 6
// 125.363 us; speedup vs baseline: 1.0944x; 1.0909x over previous
//
#include <hip/hip_runtime.h>

// Problem: B=32, N=128, T=96, H=64, TF=24. All I/O float32.
// A_norm = ones(N,N)/N => every GCN output is the node-mean (node-uniform);
// model collapses to per-batch H-vectors. Node dim only in the initial mean
// and the final broadcast.
//
// R21: restore session-best (R16 build, 125.675us). Evidence ledger:
//  - timed window = ~90us UNCONDITIONAL 256MiB poison fills (R17: persist
//    with d_ws unused; run at 84% HBM peak = their own roofline)
//    + ~4us spatial + ~35us serial ODE chain + gaps.
//  - ODE chain floor: R15 dot2 == R16 mfma+bperm == R18 split-acc == ~35us;
//    R20 DS-free (bcast-MFMA) = 44.4us (measured) => any fanout of one reg
//    to 64 lanes costs ~1 DS-latency-equivalent; MFMA-dep route is worse.
//    184 sequential layers x ~250-300cyc latency floor = the ode time.
//  - Fusion dead twice (R17 1024thr: 64-VGPR cap spill; R19 512thr: 2x
//    per-wave spatial + still 120 VGPR).

#define BN 32
#define NN 128
#define TT 96
#define HH 64
#define TFC 24

#if defined(__has_builtin)
#if __has_builtin(__builtin_amdgcn_fdot2)
#define HAVE_FDOT2 1
#endif
#if __has_builtin(__builtin_amdgcn_update_dpp)
#define HAVE_DPP 1
#endif
#endif

using half2v = __fp16 __attribute__((ext_vector_type(2)));
typedef _Float16 half8 __attribute__((ext_vector_type(8)));
typedef float f32x4 __attribute__((ext_vector_type(4)));

__device__ __forceinline__ unsigned pack_pair(float a, float b) {
    union { half2v h; unsigned u; } c;
    c.h = __builtin_amdgcn_cvt_pkrtz(a, b);
    return c.u;
}
__device__ __forceinline__ half2v as_h2(unsigned u) {
    union { unsigned u; half2v h; } c; c.u = u; return c.h;
}
__device__ __forceinline__ unsigned rdlu(unsigned v, int l) {
    return (unsigned)__builtin_amdgcn_readlane((int)v, l);
}
__device__ __forceinline__ float rdl(float v, int l) {
    return __int_as_float(__builtin_amdgcn_readlane(__float_as_int(v), l));
}

template <int CTRL>
__device__ __forceinline__ float dppf(float x) {
#if HAVE_DPP
    return __int_as_float(
        __builtin_amdgcn_update_dpp(0, __float_as_int(x), CTRL, 0xF, 0xF, true));
#else
    return 0.f;  // unused
#endif
}

__device__ __forceinline__ float xor1(float x) {
#if HAVE_DPP
    return dppf<0xB1>(x);          // quad_perm [1,0,3,2] — VALU pipe
#else
    return __shfl_xor(x, 1, 64);
#endif
}

__device__ __forceinline__ float wave_sum(float v) {
#if HAVE_DPP
    v += dppf<0xB1>(v);
    v += dppf<0x4E>(v);
    v += dppf<0x141>(v);
    v += dppf<0x140>(v);
    return ((rdl(v, 0) + rdl(v, 16)) + (rdl(v, 32) + rdl(v, 48)));
#else
#pragma unroll
    for (int off = 32; off > 0; off >>= 1) v += __shfl_xor(v, off, 64);
    return v;
#endif
}
__device__ __forceinline__ void wave_sum2(float& a, float& b) {
#if HAVE_DPP
    a += dppf<0xB1>(a);  b += dppf<0xB1>(b);
    a += dppf<0x4E>(a);  b += dppf<0x4E>(b);
    a += dppf<0x141>(a); b += dppf<0x141>(b);
    a += dppf<0x140>(a); b += dppf<0x140>(b);
    a = (rdl(a, 0) + rdl(a, 16)) + (rdl(a, 32) + rdl(a, 48));
    b = (rdl(b, 0) + rdl(b, 16)) + (rdl(b, 32) + rdl(b, 48));
#else
    a = wave_sum(a); b = wave_sum(b);
#endif
}
__device__ __forceinline__ float wave_max(float v) {
#if HAVE_DPP
    v = fmaxf(v, dppf<0xB1>(v));
    v = fmaxf(v, dppf<0x4E>(v));
    v = fmaxf(v, dppf<0x141>(v));
    v = fmaxf(v, dppf<0x140>(v));
    return fmaxf(fmaxf(rdl(v, 0), rdl(v, 16)), fmaxf(rdl(v, 32), rdl(v, 48)));
#else
#pragma unroll
    for (int off = 32; off > 0; off >>= 1) v = fmaxf(v, __shfl_xor(v, off, 64));
    return v;
#endif
}

__device__ __forceinline__ float dot2acc(unsigned w, unsigned up, float acc) {
#if HAVE_FDOT2
    return __builtin_amdgcn_fdot2(as_h2(w), as_h2(up), acc, false);
#else
    const half2v wh = as_h2(w), uh = as_h2(up);
    return fmaf((float)wh.y, (float)uh.y, fmaf((float)wh.x, (float)uh.x, acc));
#endif
}

// Dual-stream matvec (shared weights) for the spatial phase.
#define PMV64_2(WP, UA, UB, RA, RB)                                        \
    do {                                                                   \
        float a0 = 0.f, a1 = 0.f, a2 = 0.f, a3 = 0.f;                      \
        float b0 = 0.f, b1 = 0.f, b2 = 0.f, b3 = 0.f;                      \
        _Pragma("unroll")                                                  \
        for (int k = 0; k < 32; k += 4) {                                  \
            const unsigned ua0 = rdlu(UA, 2 * k);                          \
            const unsigned ub0 = rdlu(UB, 2 * k);                          \
            const unsigned ua1 = rdlu(UA, 2 * k + 2);                      \
            const unsigned ub1 = rdlu(UB, 2 * k + 2);                      \
            const unsigned ua2 = rdlu(UA, 2 * k + 4);                      \
            const unsigned ub2 = rdlu(UB, 2 * k + 4);                      \
            const unsigned ua3 = rdlu(UA, 2 * k + 6);                      \
            const unsigned ub3 = rdlu(UB, 2 * k + 6);                      \
            a0 = dot2acc(WP[k],     ua0, a0);                              \
            b0 = dot2acc(WP[k],     ub0, b0);                              \
            a1 = dot2acc(WP[k + 1], ua1, a1);                              \
            b1 = dot2acc(WP[k + 1], ub1, b1);                              \
            a2 = dot2acc(WP[k + 2], ua2, a2);                              \
            b2 = dot2acc(WP[k + 2], ub2, b2);                              \
            a3 = dot2acc(WP[k + 3], ua3, a3);                              \
            b3 = dot2acc(WP[k + 3], ub3, b3);                              \
        }                                                                  \
        RA = (a0 + a1) + (a2 + a3);                                        \
        RB = (b0 + b1) + (b2 + b3);                                        \
    } while (0)

// No clamp: x->+inf => rcp(inf)=0 => 1; x->-inf => e=0 => -1. (R13-proven)
__device__ __forceinline__ float fast_tanh(float x) {
    float e = __expf(2.f * x);
    return 1.f - 2.f * __builtin_amdgcn_rcpf(e + 1.f);
}
__device__ __forceinline__ float fast_sigmoid(float x) {
    return __builtin_amdgcn_rcpf(1.f + __expf(-x));
}

// ============================ Kernel A ====================================
// grid (4, 32): block = (t-quarter, batch). 4 waves x 6 t (3 dual-iters).
// Writes h2 as packed f16 t-pairs and att logits to workspace.
__global__ __launch_bounds__(256) void spatial_kernel(
    const float* __restrict__ x,    const float* __restrict__ Ws1,
    const float* __restrict__ bs1,  const float* __restrict__ Ws2,
    const float* __restrict__ bs2,  const float* __restrict__ Wa1,
    const float* __restrict__ ba1,  const float* __restrict__ Wa2,
    unsigned* __restrict__ ws_h2,   float* __restrict__ ws_att)
{
    const int tid  = threadIdx.x;
    const int lane = tid & 63;
    const int w    = tid >> 6;
    const int tq   = blockIdx.x;
    const int b    = blockIdx.y;
    const int tbase = tq * 24;

    __shared__ float xbar[24];
    if (tid < 24) {
        const float* xb = x + (size_t)b * NN * TT + (tbase + tid);
        float s = 0.f;
#pragma unroll
        for (int n = 0; n < NN; ++n) s += xb[n * TT];
        xbar[tid] = s * (1.f / 128.f);
    }

    const float ws1l = Ws1[lane];
    const float bs1l = bs1[lane];
    const float bs2l = bs2[lane];
    const float ba1l = ba1[lane];
    const float wa2l = Wa2[lane];
    unsigned ws2p[32], wa1p[32];
#pragma unroll
    for (int k = 0; k < 32; ++k) {
        ws2p[k] = pack_pair(Ws2[(2 * k) * HH + lane], Ws2[(2 * k + 1) * HH + lane]);
        wa1p[k] = pack_pair(Wa1[(2 * k) * HH + lane], Wa1[(2 * k + 1) * HH + lane]);
    }
#pragma unroll
    for (int k = 0; k < 32; ++k) {
        asm volatile("" : "+v"(ws2p[k]), "+v"(wa1p[k]));
    }
    __syncthreads();   // xbar ready

#pragma unroll 1
    for (int i = 0; i < 3; ++i) {
        const int tl0 = w * 6 + 2 * i;          // local t (even)
        const float sA = xbar[tl0];
        const float sB = xbar[tl0 + 1];
        const float h1A = fmaxf(fmaf(sA, ws1l, bs1l), 0.f);
        const float h1B = fmaxf(fmaf(sB, ws1l, bs1l), 0.f);
        const unsigned uA = pack_pair(h1A, xor1(h1A));
        const unsigned uB = pack_pair(h1B, xor1(h1B));
        float accA, accB;
        PMV64_2(ws2p, uA, uB, accA, accB);
        const float h2A = fmaxf(accA + bs2l, 0.f);
        const float h2B = fmaxf(accB + bs2l, 0.f);
        // h2 pair over adjacent t: element tp = (tbase+tl0)/2
        ws_h2[((size_t)b * (TT / 2) + (tbase + tl0) / 2) * HH + lane] =
            pack_pair(h2A, h2B);

        const unsigned vA = pack_pair(h2A, xor1(h2A));
        const unsigned vB = pack_pair(h2B, xor1(h2B));
        PMV64_2(wa1p, vA, vB, accA, accB);
        float gA = fast_tanh(accA + ba1l) * wa2l;
        float gB = fast_tanh(accB + ba1l) * wa2l;
        wave_sum2(gA, gB);                       // ba2: shift-invariant
        if (lane == 0) {
            ws_att[b * TT + tbase + tl0]     = gA;
            ws_att[b * TT + tbase + tl0 + 1] = gB;
        }
    }
}

// ============================ Kernel B ====================================
// grid 32 x 64 threads: softmax + nf + GRU + 23 RK4 steps + head.
__global__ __launch_bounds__(64)
__attribute__((amdgpu_waves_per_eu(1, 1)))
void ode_kernel(
    const unsigned* __restrict__ ws_h2, const float* __restrict__ ws_att,
    const float* __restrict__ Wih,  const float* __restrict__ bih,
    const float* __restrict__ bhh,  const float* __restrict__ Wo1,
    const float* __restrict__ bo1p, const float* __restrict__ Wo2,
    const float* __restrict__ bo2p, const float* __restrict__ Wout,
    const float* __restrict__ boutp, float* __restrict__ out)
{
    const int lane = threadIdx.x;
    const int b    = blockIdx.x;

    // ---- softmax over t (96 logits: lane t, lane 64+t for t<32) ----
    const float a0s = ws_att[b * TT + lane];
    const float a1s = (lane < TT - 64) ? ws_att[b * TT + 64 + lane] : -1e30f;
    const float m = wave_max(fmaxf(a0s, a1s));
    const float e0 = __expf(a0s - m);
    const float e1 = (lane < TT - 64) ? __expf(a1s - m) : 0.f;
    const float inv = __builtin_amdgcn_rcpf(wave_sum(e0 + e1));
    const float q0 = e0 * inv;      // weight for t = lane
    const float q1 = e1 * inv;      // weight for t = 64 + lane (lane < 32)

    // ---- nf[lane] = sum_t w[t]*h2[t][lane] via packed t-pairs + dot2 ----
    const unsigned* h2b = ws_h2 + (size_t)b * (TT / 2) * HH;
    unsigned hp[TT / 2];
#pragma unroll
    for (int tp = 0; tp < TT / 2; ++tp) hp[tp] = h2b[tp * HH + lane];
    float nf = 0.f;
#pragma unroll
    for (int tp = 0; tp < 32; ++tp) {
        const unsigned qp = pack_pair(rdl(q0, 2 * tp), rdl(q0, 2 * tp + 1));
        nf = dot2acc(hp[tp], qp, nf);
    }
#pragma unroll
    for (int tp = 32; tp < TT / 2; ++tp) {
        const unsigned qp = pack_pair(rdl(q1, 2 * tp - 64), rdl(q1, 2 * tp - 63));
        nf = dot2acc(hp[tp], qp, nf);
    }

    // ---- one-step GRU, h0=0 (W_hh matmul vanishes; b_hh biases remain) ----
    float gr = bih[lane];
    float gz = bih[64 + lane];
    float gn = bih[128 + lane];
#pragma unroll
    for (int j = 0; j < HH; j += 4) {
        const float4 wr = *(const float4*)&Wih[(size_t)lane * HH + j];
        const float4 wz = *(const float4*)&Wih[(size_t)(64 + lane) * HH + j];
        const float4 wn = *(const float4*)&Wih[(size_t)(128 + lane) * HH + j];
        const float n0 = rdl(nf, j), n1 = rdl(nf, j + 1);
        const float n2 = rdl(nf, j + 2), n3 = rdl(nf, j + 3);
        gr += n0 * wr.x + n1 * wr.y + n2 * wr.z + n3 * wr.w;
        gz += n0 * wz.x + n1 * wz.y + n2 * wz.z + n3 * wz.w;
        gn += n0 * wn.x + n1 * wn.y + n2 * wn.z + n3 * wn.w;
    }
    const float r = fast_sigmoid(gr + bhh[lane]);
    const float z = fast_sigmoid(gz + bhh[64 + lane]);
    const float n = fast_tanh(gn + r * bhh[128 + lane]);
    float y = (1.f - z) * n;

    // ---- ODE weights as MFMA B-fragments (resident in VGPRs) ----
    // v_mfma_f32_16x16x32_f16: C[16,16] = A[16,32]*B[32,16] + C.
    // A/B built with the IDENTICAL (group,reg)->k map so any shared
    // k-permutation cancels; C select via m89-verified col=lane&15 map.
    const int col16 = lane & 15;
    const int grp   = lane >> 4;
    union Frag { unsigned u4[4]; half8 h; };
    Frag B1[4][2], B2[4][2];          // [N-tile][K-step]
#pragma unroll
    for (int t = 0; t < 4; ++t) {
#pragma unroll
        for (int s = 0; s < 2; ++s) {
#pragma unroll
            for (int rr = 0; rr < 4; ++rr) {
                const int k = 32 * s + 8 * grp + 2 * rr;
                const int j = 16 * t + col16;
                B1[t][s].u4[rr] = pack_pair(Wo1[k * HH + j], Wo1[(k + 1) * HH + j]);
                B2[t][s].u4[rr] = pack_pair(Wo2[k * HH + j], Wo2[(k + 1) * HH + j]);
            }
        }
    }
#pragma unroll
    for (int t = 0; t < 4; ++t) {
#pragma unroll
        for (int s = 0; s < 2; ++s) {
            asm volatile("" : "+v"(B1[t][s].h), "+v"(B2[t][s].h));
        }
    }
    const float bo1 = bo1p[lane];
    const float bo2 = bo2p[lane];
    const float wo  = Wout[lane];
    const float bo  = boutp[0];

    // bpermute byte addresses: A k-step 0 pulls pair m=4*grp+r from lane 2m;
    // k-step 1 pulls pair 16+4*grp+r (lanes 32..62).
    const int ab0 = 32 * grp;
    const bool s1 = (grp == 1), s2 = (grp == 2), s3 = (grp == 3);
    const f32x4 CZERO = {0.f, 0.f, 0.f, 0.f};

    auto f_eval = [&](float u) -> float {
        // ---- layer 1 ----
        Frag A0, A1;
        const unsigned up = pack_pair(u, xor1(u));   // even lane 2m: (u[2m],u[2m+1])
#pragma unroll
        for (int rr = 0; rr < 4; ++rr) {
            A0.u4[rr] = (unsigned)__builtin_amdgcn_ds_bpermute(ab0 + 8 * rr, (int)up);
            A1.u4[rr] = (unsigned)__builtin_amdgcn_ds_bpermute(ab0 + 128 + 8 * rr, (int)up);
        }
        f32x4 c0 = __builtin_amdgcn_mfma_f32_16x16x32_f16(A0.h, B1[0][0].h, CZERO, 0, 0, 0);
        f32x4 c1 = __builtin_amdgcn_mfma_f32_16x16x32_f16(A0.h, B1[1][0].h, CZERO, 0, 0, 0);
        f32x4 c2 = __builtin_amdgcn_mfma_f32_16x16x32_f16(A0.h, B1[2][0].h, CZERO, 0, 0, 0);
        f32x4 c3 = __builtin_amdgcn_mfma_f32_16x16x32_f16(A0.h, B1[3][0].h, CZERO, 0, 0, 0);
        c0 = __builtin_amdgcn_mfma_f32_16x16x32_f16(A1.h, B1[0][1].h, c0, 0, 0, 0);
        c1 = __builtin_amdgcn_mfma_f32_16x16x32_f16(A1.h, B1[1][1].h, c1, 0, 0, 0);
        c2 = __builtin_amdgcn_mfma_f32_16x16x32_f16(A1.h, B1[2][1].h, c2, 0, 0, 0);
        c3 = __builtin_amdgcn_mfma_f32_16x16x32_f16(A1.h, B1[3][1].h, c3, 0, 0, 0);
        float v = s1 ? c1[0] : c0[0];
        v = s2 ? c2[0] : v;
        v = s3 ? c3[0] : v;                 // out[lane], rows redundant
        v = fast_tanh(v + bo1);
        // ---- layer 2 ----
        const unsigned vp = pack_pair(v, xor1(v));
#pragma unroll
        for (int rr = 0; rr < 4; ++rr) {
            A0.u4[rr] = (unsigned)__builtin_amdgcn_ds_bpermute(ab0 + 8 * rr, (int)vp);
            A1.u4[rr] = (unsigned)__builtin_amdgcn_ds_bpermute(ab0 + 128 + 8 * rr, (int)vp);
        }
        c0 = __builtin_amdgcn_mfma_f32_16x16x32_f16(A0.h, B2[0][0].h, CZERO, 0, 0, 0);
        c1 = __builtin_amdgcn_mfma_f32_16x16x32_f16(A0.h, B2[1][0].h, CZERO, 0, 0, 0);
        c2 = __builtin_amdgcn_mfma_f32_16x16x32_f16(A0.h, B2[2][0].h, CZERO, 0, 0, 0);
        c3 = __builtin_amdgcn_mfma_f32_16x16x32_f16(A0.h, B2[3][0].h, CZERO, 0, 0, 0);
        c0 = __builtin_amdgcn_mfma_f32_16x16x32_f16(A1.h, B2[0][1].h, c0, 0, 0, 0);
        c1 = __builtin_amdgcn_mfma_f32_16x16x32_f16(A1.h, B2[1][1].h, c1, 0, 0, 0);
        c2 = __builtin_amdgcn_mfma_f32_16x16x32_f16(A1.h, B2[2][1].h, c2, 0, 0, 0);
        c3 = __builtin_amdgcn_mfma_f32_16x16x32_f16(A1.h, B2[3][1].h, c3, 0, 0, 0);
        float o = s1 ? c1[0] : c0[0];
        o = s2 ? c2[0] : o;
        o = s3 ? c3[0] : o;
        return fast_tanh(o + bo2);
    };

    float* ob = out + (size_t)b * NN * TFC;
    {
        const float p = wave_sum(y * wo) + bo;     // traj[0] = hidden
        ob[lane * TFC]        = p;
        ob[(64 + lane) * TFC] = p;
    }

    const float dt = (float)(24.0 / 23.0);
    const float third = 1.f / 3.f;

#pragma unroll 1
    for (int st = 0; st < TFC - 1; ++st) {
        const float k1 = f_eval(y);
        const float k2 = f_eval(y + dt * k1 * third);
        const float k3 = f_eval(y + dt * (k2 - k1 * third));
        const float k4 = f_eval(y + dt * (k1 - k2 + k3));
        y = y + dt * (k1 + 3.f * (k2 + k3) + k4) * 0.125f;
        const float p = wave_sum(y * wo) + bo;
        ob[lane * TFC + st + 1]        = p;
        ob[(64 + lane) * TFC + st + 1] = p;
    }
}

extern "C" void kernel_launch(void* const* d_in, const int* in_sizes, int n_in,
                              void* d_out, int out_size, void* d_ws, size_t ws_size,
                              hipStream_t stream) {
    (void)in_sizes; (void)n_in; (void)ws_size; (void)out_size;
    const float* x    = (const float*)d_in[0];
    const float* Ws1  = (const float*)d_in[1];
    const float* bs1  = (const float*)d_in[2];
    const float* Ws2  = (const float*)d_in[3];
    const float* bs2  = (const float*)d_in[4];
    const float* Wa1  = (const float*)d_in[5];
    const float* ba1  = (const float*)d_in[6];
    const float* Wa2  = (const float*)d_in[7];
    // d_in[8]  = ba2  : unused (softmax shift-invariant)
    const float* Wih  = (const float*)d_in[9];
    // d_in[10] = W_hh : unused (h0 = 0)
    const float* bih  = (const float*)d_in[11];
    const float* bhh  = (const float*)d_in[12];
    const float* Wo1  = (const float*)d_in[13];
    const float* bo1  = (const float*)d_in[14];
    const float* Wo2  = (const float*)d_in[15];
    const float* bo2  = (const float*)d_in[16];
    const float* Wout = (const float*)d_in[17];
    const float* bout = (const float*)d_in[18];

    unsigned* ws_h2 = (unsigned*)d_ws;                       // 32*48*64*4 = 384KB
    float* ws_att   = (float*)((char*)d_ws + (size_t)BN * (TT / 2) * HH * 4);

    spatial_kernel<<<dim3(4, BN), dim3(256), 0, stream>>>(
        x, Ws1, bs1, Ws2, bs2, Wa1, ba1, Wa2, ws_h2, ws_att);

    ode_kernel<<<dim3(BN), dim3(64), 0, stream>>>(
        ws_h2, ws_att, Wih, bih, bhh, Wo1, bo1, Wo2, bo2, Wout, bout,
        (float*)d_out);
}